// Round 2
// baseline (429.298 us; speedup 1.0000x reference)
//
#include <hip/hip_runtime.h>

#define DIM 128
#define CPT 128               // chars per stream
#define SPB 8                 // streams per block (8 * 32 lanes = 256 threads)

// out = N - <H,T>_F / (||H||_F * ||T||_F); T never materialized.
// Scan blocks: stream = 32 lanes, lane owns 4 columns (float4). Stream s owns
// chars [s*CPT, s*CPT+CPT): processes every segment that STARTS in its range
// (skips leading continuation, extends past the end for its last segment).
// On each segment end: ht += <h[head[seg]], acc>, tt += <acc,acc>.
// hh blocks: grid-stride over all rows, hh += <h,h> (covers empty segments).
__global__ __launch_bounds__(256) void fused_kernel(
    const float* __restrict__ char_emb,
    const float* __restrict__ ent,
    const int* __restrict__ head_ids,
    const int* __restrict__ char_ids,
    const int* __restrict__ seg_ids,
    double* __restrict__ sums,   // [0]=ht [1]=hh [2]=tt
    int total_chars, int n_triples, int n_scan_blocks)
{
    __shared__ int s_cid[SPB][CPT];
    __shared__ int s_sid[SPB][CPT];
    const int lane32 = threadIdx.x & 31;
    const int sidx   = threadIdx.x >> 5;

    float ht = 0.f, tt = 0.f, hh = 0.f;

    if (blockIdx.x < (unsigned)n_scan_blocks) {
        // ---------------- scan role ----------------
        const long stream = (long)blockIdx.x * SPB + sidx;
        const int start = (int)(stream * CPT);
        const int nn = min(CPT, total_chars - start);

        if (nn > 0) {
            for (int i = lane32; i < nn; i += 32) {
                s_cid[sidx][i] = char_ids[start + i];
                s_sid[sidx][i] = seg_ids[start + i];
            }
        }
        __syncthreads();

        if (nn > 0) {
            // skip chars continuing a segment that started in a prior chunk
            int p = 0;
            if (start > 0) {
                const int prev = seg_ids[start - 1];
                while (p < nn && s_sid[sidx][p] == prev) ++p;
            }
            if (p < nn) {
                int cur = s_sid[sidx][p];
                float4 acc = make_float4(0.f, 0.f, 0.f, 0.f);

                int c = p;
                while (c < nn) {
                    const int m = min(4, nn - c);
                    float4 v[4];
#pragma unroll
                    for (int j = 0; j < 4; ++j) {
                        if (j < m)
                            v[j] = ((const float4*)(char_emb +
                                    (size_t)s_cid[sidx][c + j] * DIM))[lane32];
                    }
                    for (int j = 0; j < m; ++j) {
                        const int seg = s_sid[sidx][c + j];
                        if (seg != cur) {
                            // flush finished segment
                            const int hrow = head_ids[cur];
                            const float4 hv = ((const float4*)(ent +
                                              (size_t)hrow * DIM))[lane32];
                            ht += hv.x * acc.x + hv.y * acc.y +
                                  hv.z * acc.z + hv.w * acc.w;
                            tt += acc.x * acc.x + acc.y * acc.y +
                                  acc.z * acc.z + acc.w * acc.w;
                            acc = make_float4(0.f, 0.f, 0.f, 0.f);
                            cur = seg;
                        }
                        acc.x += v[j].x; acc.y += v[j].y;
                        acc.z += v[j].z; acc.w += v[j].w;
                    }
                    c += m;
                }
                // tail: last segment may continue into following chunks
                int g = start + nn;
                while (g < total_chars) {
                    if (seg_ids[g] != cur) break;
                    const float4 v = ((const float4*)(char_emb +
                                     (size_t)char_ids[g] * DIM))[lane32];
                    acc.x += v.x; acc.y += v.y; acc.z += v.z; acc.w += v.w;
                    ++g;
                }
                // final flush
                const int hrow = head_ids[cur];
                const float4 hv = ((const float4*)(ent +
                                  (size_t)hrow * DIM))[lane32];
                ht += hv.x * acc.x + hv.y * acc.y +
                      hv.z * acc.z + hv.w * acc.w;
                tt += acc.x * acc.x + acc.y * acc.y +
                      acc.z * acc.z + acc.w * acc.w;
            }
        }
    } else {
        // ---------------- hh role ----------------
        const int n_hh_blocks = gridDim.x - n_scan_blocks;
        const int streams = n_hh_blocks * SPB;
        const int my = (blockIdx.x - n_scan_blocks) * SPB + sidx;
        for (int row = my; row < n_triples; row += streams) {
            const int hrow = head_ids[row];
            const float4 hv = ((const float4*)(ent +
                              (size_t)hrow * DIM))[lane32];
            hh += hv.x * hv.x + hv.y * hv.y + hv.z * hv.z + hv.w * hv.w;
        }
    }

    // ------------- block reduction + atomic -------------
#pragma unroll
    for (int off = 32; off > 0; off >>= 1) {
        ht += __shfl_down(ht, off);
        tt += __shfl_down(tt, off);
        hh += __shfl_down(hh, off);
    }
    __shared__ float r_ht[4], r_tt[4], r_hh[4];
    const int wave = threadIdx.x >> 6;
    if ((threadIdx.x & 63) == 0) {
        r_ht[wave] = ht; r_tt[wave] = tt; r_hh[wave] = hh;
    }
    __syncthreads();
    if (threadIdx.x == 0) {
        float a = 0.f, b = 0.f, c = 0.f;
#pragma unroll
        for (int w = 0; w < 4; ++w) { a += r_ht[w]; b += r_tt[w]; c += r_hh[w]; }
        if (a != 0.f) atomicAdd(&sums[0], (double)a);
        if (c != 0.f) atomicAdd(&sums[1], (double)c);
        if (b != 0.f) atomicAdd(&sums[2], (double)b);
    }
}

// out = N - ht / (sqrt(hh) * sqrt(tt))
__global__ void finalize_kernel(const double* __restrict__ sums,
                                float* __restrict__ out, int n_triples)
{
    const double ht = sums[0], hh = sums[1], tt = sums[2];
    out[0] = (float)((double)n_triples - ht / sqrt(hh * tt));
}

extern "C" void kernel_launch(void* const* d_in, const int* in_sizes, int n_in,
                              void* d_out, int out_size, void* d_ws, size_t ws_size,
                              hipStream_t stream)
{
    const float* char_emb = (const float*)d_in[0];
    const float* ent_emb  = (const float*)d_in[1];
    const int* head_ids   = (const int*)d_in[2];
    const int* char_ids   = (const int*)d_in[3];
    const int* seg_ids    = (const int*)d_in[4];
    const int n_triples   = in_sizes[2];
    const int total_chars = in_sizes[3];

    double* sums = (double*)d_ws;
    hipMemsetAsync(d_ws, 0, 3 * sizeof(double), stream);

    const int n_streams = (total_chars + CPT - 1) / CPT;
    const int n_scan_blocks = (n_streams + SPB - 1) / SPB;
    const int n_hh_blocks = 64;

    fused_kernel<<<n_scan_blocks + n_hh_blocks, 256, 0, stream>>>(
        char_emb, ent_emb, head_ids, char_ids, seg_ids, sums,
        total_chars, n_triples, n_scan_blocks);

    finalize_kernel<<<1, 1, 0, stream>>>(sums, (float*)d_out, n_triples);
}

// Round 3
// 341.795 us; speedup vs baseline: 1.2560x; 1.2560x over previous
//
#include <hip/hip_runtime.h>

#define DIM 128
#define HALF 64           // columns per slice (2 slices: working set 2.56 MB < 4 MB L2/XCD)
#define CPT 256           // chars per stream (one 64-lane wave)
#define WPB 4             // waves (streams) per block

// out = N - <H,T>_F / (||H||_F * ||T||_F); T never materialized.
// Scan role: wave = one stream over CPT chars for ONE 64-column slice
// (slice = blockIdx&1 aligns with XCD parity under round-robin dispatch, so
// each XCD's L2 keeps its 2.56 MB char-table slice resident). Lane = column.
// Segment end => ht += h[head]*acc, tt += acc*acc (per-lane partials).
// hh role: grid-stride over all head rows (covers empty segments exactly).
__global__ __launch_bounds__(256) void fused_kernel(
    const float* __restrict__ char_emb,
    const float* __restrict__ ent,
    const int* __restrict__ head_ids,
    const int* __restrict__ char_ids,
    const int* __restrict__ seg_ids,
    double* __restrict__ sums,   // [0]=ht [1]=hh [2]=tt
    int total_chars, int n_triples, int n_scan_blocks)
{
    __shared__ int2 s_ids[WPB][CPT];   // (char_id, seg_id) per wave's chunk
    const int lane = threadIdx.x & 63;
    const int wid  = threadIdx.x >> 6;

    float ht = 0.f, tt = 0.f, hh = 0.f;

    if ((int)blockIdx.x < n_scan_blocks) {
        // ---------------- scan role ----------------
        const int slice = blockIdx.x & 1;
        const int cblk  = blockIdx.x >> 1;
        const int start = (cblk * WPB + wid) * CPT;
        const int nn = min(CPT, total_chars - start);
        const float* __restrict__ cemb = char_emb + slice * HALF + lane;
        const float* __restrict__ eemb = ent + slice * HALF + lane;

        if (nn > 0) {
            for (int i = lane; i < nn; i += 64) {
                s_ids[wid][i] = make_int2(char_ids[start + i], seg_ids[start + i]);
            }
        }
        __syncthreads();

        if (nn > 0) {
            // skip chars continuing a segment begun in a previous chunk
            int p = 0;
            if (start > 0) {
                const int prev = seg_ids[start - 1];
                while (p < nn && s_ids[wid][p].y == prev) ++p;
            }
            if (p < nn) {
                int cur = s_ids[wid][p].y;
                float acc = 0.f;
                int c = p;

                // full 8-batches: 8 gathers in flight, no guards
                while (c + 8 <= nn) {
                    float v[8]; int sg[8];
#pragma unroll
                    for (int j = 0; j < 8; ++j) {
                        const int2 cs = s_ids[wid][c + j];
                        v[j] = cemb[(size_t)cs.x * DIM];   // L2-resident slice
                        sg[j] = cs.y;
                    }
#pragma unroll
                    for (int j = 0; j < 8; ++j) {
                        if (sg[j] != cur) {                // wave-uniform branch
                            const int hrow = head_ids[cur];
                            const float hv = __builtin_nontemporal_load(
                                eemb + (size_t)hrow * DIM);
                            ht += hv * acc;
                            tt += acc * acc;
                            acc = 0.f;
                            cur = sg[j];
                        }
                        acc += v[j];
                    }
                    c += 8;
                }
                // remainder singles
                for (; c < nn; ++c) {
                    const int2 cs = s_ids[wid][c];
                    if (cs.y != cur) {
                        const int hrow = head_ids[cur];
                        const float hv = __builtin_nontemporal_load(
                            eemb + (size_t)hrow * DIM);
                        ht += hv * acc;
                        tt += acc * acc;
                        acc = 0.f;
                        cur = cs.y;
                    }
                    acc += cemb[(size_t)cs.x * DIM];
                }
                // tail: last segment may continue into following chunks
                int g = start + nn;
                while (g < total_chars) {
                    if (seg_ids[g] != cur) break;
                    acc += cemb[(size_t)char_ids[g] * DIM];
                    ++g;
                }
                // final flush
                {
                    const int hrow = head_ids[cur];
                    const float hv = __builtin_nontemporal_load(
                        eemb + (size_t)hrow * DIM);
                    ht += hv * acc;
                    tt += acc * acc;
                }
            }
        }
    } else {
        // ---------------- hh role ----------------
        const int nb = gridDim.x - n_scan_blocks;
        const int stride = nb * WPB;
        const float* __restrict__ e2 = ent + 2 * lane;
        for (int row = (blockIdx.x - n_scan_blocks) * WPB + wid;
             row < n_triples; row += stride) {
            const int hrow = head_ids[row];
            const float a = __builtin_nontemporal_load(e2 + (size_t)hrow * DIM);
            const float b = __builtin_nontemporal_load(e2 + (size_t)hrow * DIM + 1);
            hh += a * a + b * b;
        }
    }

    // ------------- block reduction + atomic -------------
#pragma unroll
    for (int off = 32; off > 0; off >>= 1) {
        ht += __shfl_down(ht, off);
        tt += __shfl_down(tt, off);
        hh += __shfl_down(hh, off);
    }
    __shared__ float r_ht[WPB], r_tt[WPB], r_hh[WPB];
    if (lane == 0) { r_ht[wid] = ht; r_tt[wid] = tt; r_hh[wid] = hh; }
    __syncthreads();
    if (threadIdx.x == 0) {
        float a = 0.f, b = 0.f, c = 0.f;
#pragma unroll
        for (int w = 0; w < WPB; ++w) { a += r_ht[w]; b += r_tt[w]; c += r_hh[w]; }
        if (a != 0.f) atomicAdd(&sums[0], (double)a);
        if (c != 0.f) atomicAdd(&sums[1], (double)c);
        if (b != 0.f) atomicAdd(&sums[2], (double)b);
    }
}

// out = N - ht / (sqrt(hh) * sqrt(tt))
__global__ void finalize_kernel(const double* __restrict__ sums,
                                float* __restrict__ out, int n_triples)
{
    const double ht = sums[0], hh = sums[1], tt = sums[2];
    out[0] = (float)((double)n_triples - ht / sqrt(hh * tt));
}

extern "C" void kernel_launch(void* const* d_in, const int* in_sizes, int n_in,
                              void* d_out, int out_size, void* d_ws, size_t ws_size,
                              hipStream_t stream)
{
    const float* char_emb = (const float*)d_in[0];
    const float* ent_emb  = (const float*)d_in[1];
    const int* head_ids   = (const int*)d_in[2];
    const int* char_ids   = (const int*)d_in[3];
    const int* seg_ids    = (const int*)d_in[4];
    const int n_triples   = in_sizes[2];
    const int total_chars = in_sizes[3];

    double* sums = (double*)d_ws;
    hipMemsetAsync(d_ws, 0, 3 * sizeof(double), stream);

    const int n_streams = (total_chars + CPT - 1) / CPT;
    const int blocks_per_slice = (n_streams + WPB - 1) / WPB;
    const int n_scan_blocks = 2 * blocks_per_slice;
    const int n_hh_blocks = 128;

    fused_kernel<<<n_scan_blocks + n_hh_blocks, 256, 0, stream>>>(
        char_emb, ent_emb, head_ids, char_ids, seg_ids, sums,
        total_chars, n_triples, n_scan_blocks);

    finalize_kernel<<<1, 1, 0, stream>>>(sums, (float*)d_out, n_triples);
}

// Round 4
// 276.878 us; speedup vs baseline: 1.5505x; 1.2345x over previous
//
#include <hip/hip_runtime.h>

#define DIM 128
#define HALF 64           // columns per slice; 2 slices -> 2.56 MB char slice per XCD L2
#define CPT 256           // chars per stream (one 64-lane wave)
#define TAIL 64           // extra staged ids for cross-chunk tail
#define WPB 4             // waves per block (256 threads)

// out = N - <H,T>_F / (||H||_F * ||T||_F); T never materialized.
// ht/tt from run-scan over sorted segment_ids; hh over all head rows.
__global__ __launch_bounds__(256) void fused_kernel(
    const float* __restrict__ char_emb,
    const float* __restrict__ ent,
    const int* __restrict__ head_ids,
    const int* __restrict__ char_ids,
    const int* __restrict__ seg_ids,
    double* __restrict__ sums,   // [0]=ht [1]=hh [2]=tt
    int total_chars, int n_triples, int n_scan_blocks)
{
    __shared__ int2 s_ids[WPB][CPT + TAIL];   // (char_id, seg_id)
    const int lane = threadIdx.x & 63;
    const int wid  = threadIdx.x >> 6;

    float ht = 0.f, tt = 0.f, hh = 0.f;

    if ((int)blockIdx.x < n_scan_blocks) {
        // ---------------- scan role ----------------
        const int slice = blockIdx.x & 1;      // matches XCD parity (round-robin)
        const int cblk  = blockIdx.x >> 1;
        const int start = (cblk * WPB + wid) * CPT;
        const int nn = min(CPT, total_chars - start);
        const int sl = min(CPT + TAIL, total_chars - start);  // staged length
        const float* __restrict__ cemb = char_emb + slice * HALF + lane;
        const float* __restrict__ eemb = ent + slice * HALF + lane;

        if (nn > 0) {
            for (int i = lane; i < sl; i += 64) {
                s_ids[wid][i] = make_int2(char_ids[start + i], seg_ids[start + i]);
            }
        }
        __syncthreads();

        if (nn > 0) {
            // ---- skip continuation prefix (ballot scan, no serial loop) ----
            int p = 0;
            if (start > 0) {
                const int prev = seg_ids[start - 1];
                p = -1;
                for (int base = 0; base < nn; base += 64) {
                    const int idx = base + lane;
                    const bool differ = (idx < nn) && (s_ids[wid][idx].y != prev);
                    const unsigned long long m = __ballot(differ);
                    if (m) { p = base + (__ffsll((long long)m) - 1); break; }
                }
                if (p < 0) p = nn;   // whole chunk is continuation
            }

            if (p < nn) {
                int cur = s_ids[wid][p].y;
                // prefetch head row for current segment (used at flush)
                float hv = eemb[(size_t)head_ids[__builtin_amdgcn_readfirstlane(cur)] * DIM];
                float acc = 0.f;
                int c = p;

                float v[8]; int sg[8];
                // prologue: first batch in flight
                const bool have0 = (c + 8 <= nn);
                if (have0) {
#pragma unroll
                    for (int j = 0; j < 8; ++j) {
                        const int2 cs = s_ids[wid][c + j];
                        v[j] = cemb[(size_t)cs.x * DIM];
                        sg[j] = cs.y;
                    }
                }
                while (c + 8 <= nn) {
                    float v2[8]; int sg2[8];
                    const bool have_next = (c + 16 <= nn);
                    if (have_next) {
#pragma unroll
                        for (int j = 0; j < 8; ++j) {
                            const int2 cs = s_ids[wid][c + 8 + j];
                            v2[j] = cemb[(size_t)cs.x * DIM];  // next batch in flight
                            sg2[j] = cs.y;
                        }
                    }
#pragma unroll
                    for (int j = 0; j < 8; ++j) {
                        if (sg[j] != cur) {               // wave-uniform
                            ht += hv * acc;
                            tt += acc * acc;
                            acc = 0.f;
                            cur = sg[j];
                            hv = eemb[(size_t)head_ids[
                                __builtin_amdgcn_readfirstlane(cur)] * DIM];
                        }
                        acc += v[j];
                    }
                    if (have_next) {
#pragma unroll
                        for (int j = 0; j < 8; ++j) { v[j] = v2[j]; sg[j] = sg2[j]; }
                    }
                    c += 8;
                }
                // remainder singles (staged, <8)
                for (; c < nn; ++c) {
                    const int2 cs = s_ids[wid][c];
                    if (cs.y != cur) {
                        ht += hv * acc;
                        tt += acc * acc;
                        acc = 0.f;
                        cur = cs.y;
                        hv = eemb[(size_t)head_ids[
                            __builtin_amdgcn_readfirstlane(cur)] * DIM];
                    }
                    acc += cemb[(size_t)cs.x * DIM];
                }

                // ---- tail: last segment may continue past the chunk ----
                int g = nn;
                bool ended = false;
                while (g < sl) {
                    const int idx = g + lane;
                    const bool differ = (idx < sl) && (s_ids[wid][idx].y != cur);
                    const unsigned long long m = __ballot(differ);
                    const int run = m ? (__ffsll((long long)m) - 1)
                                      : min(64, sl - g);
                    int j = 0;
                    while (j < run) {
                        const int mm = min(8, run - j);
                        float vv[8];
#pragma unroll
                        for (int k = 0; k < 8; ++k) {
                            if (k < mm)
                                vv[k] = cemb[(size_t)s_ids[wid][g + j + k].x * DIM];
                        }
                        for (int k = 0; k < mm; ++k) acc += vv[k];
                        j += mm;
                    }
                    g += run;
                    if (m) { ended = true; break; }
                }
                if (!ended && start + sl < total_chars) {
                    // very long run past staged window: rare fallback
                    int gg = start + sl;
                    while (gg < total_chars && seg_ids[gg] == cur) {
                        acc += cemb[(size_t)char_ids[gg] * DIM];
                        ++gg;
                    }
                }
                // final flush
                ht += hv * acc;
                tt += acc * acc;
            }
        }
    } else {
        // ---------------- hh role ----------------
        const int nb = gridDim.x - n_scan_blocks;
        const int stride = nb * WPB;
        const float* __restrict__ e2 = ent + 2 * lane;
        for (int row = (blockIdx.x - n_scan_blocks) * WPB + wid;
             row < n_triples; row += stride) {
            const int hrow = head_ids[row];
            const float a = e2[(size_t)hrow * DIM];
            const float b = e2[(size_t)hrow * DIM + 1];
            hh += a * a + b * b;
        }
    }

    // ------------- block reduction + atomic -------------
#pragma unroll
    for (int off = 32; off > 0; off >>= 1) {
        ht += __shfl_down(ht, off);
        tt += __shfl_down(tt, off);
        hh += __shfl_down(hh, off);
    }
    __shared__ float r_ht[WPB], r_tt[WPB], r_hh[WPB];
    if (lane == 0) { r_ht[wid] = ht; r_tt[wid] = tt; r_hh[wid] = hh; }
    __syncthreads();
    if (threadIdx.x == 0) {
        float a = 0.f, b = 0.f, c = 0.f;
#pragma unroll
        for (int w = 0; w < WPB; ++w) { a += r_ht[w]; b += r_tt[w]; c += r_hh[w]; }
        if (a != 0.f) atomicAdd(&sums[0], (double)a);
        if (c != 0.f) atomicAdd(&sums[1], (double)c);
        if (b != 0.f) atomicAdd(&sums[2], (double)b);
    }
}

// out = N - ht / (sqrt(hh) * sqrt(tt))
__global__ void finalize_kernel(const double* __restrict__ sums,
                                float* __restrict__ out, int n_triples)
{
    const double ht = sums[0], hh = sums[1], tt = sums[2];
    out[0] = (float)((double)n_triples - ht / sqrt(hh * tt));
}

extern "C" void kernel_launch(void* const* d_in, const int* in_sizes, int n_in,
                              void* d_out, int out_size, void* d_ws, size_t ws_size,
                              hipStream_t stream)
{
    const float* char_emb = (const float*)d_in[0];
    const float* ent_emb  = (const float*)d_in[1];
    const int* head_ids   = (const int*)d_in[2];
    const int* char_ids   = (const int*)d_in[3];
    const int* seg_ids    = (const int*)d_in[4];
    const int n_triples   = in_sizes[2];
    const int total_chars = in_sizes[3];

    double* sums = (double*)d_ws;
    hipMemsetAsync(d_ws, 0, 3 * sizeof(double), stream);

    const int n_streams = (total_chars + CPT - 1) / CPT;
    const int blocks_per_slice = (n_streams + WPB - 1) / WPB;
    const int n_scan_blocks = 2 * blocks_per_slice;
    const int n_hh_blocks = 128;

    fused_kernel<<<n_scan_blocks + n_hh_blocks, 256, 0, stream>>>(
        char_emb, ent_emb, head_ids, char_ids, seg_ids, sums,
        total_chars, n_triples, n_scan_blocks);

    finalize_kernel<<<1, 1, 0, stream>>>(sums, (float*)d_out, n_triples);
}

// Round 5
// 228.675 us; speedup vs baseline: 1.8773x; 1.2108x over previous
//
#include <hip/hip_runtime.h>

#define DIM 128
#define HALF 64           // columns per slice; 2 slices -> 2.56 MB char slice per XCD L2
#define CPT 256           // chars per stream (one 64-lane wave)
#define TAIL 64           // extra staged ids for cross-chunk tail
#define WPB 4             // waves per block (256 threads)
#define BATCH 16          // gathers in flight per pipeline stage (32 outstanding)

// out = N - <H,T>_F / (||H||_F * ||T||_F); T never materialized.
// ht/tt from run-scan over sorted segment_ids; hh over all head rows.
__global__ __launch_bounds__(256) void fused_kernel(
    const float* __restrict__ char_emb,
    const float* __restrict__ ent,
    const int* __restrict__ head_ids,
    const int* __restrict__ char_ids,
    const int* __restrict__ seg_ids,
    double* __restrict__ sums,   // [0]=ht [1]=hh [2]=tt
    int total_chars, int n_triples, int n_scan_blocks)
{
    __shared__ int2 s_ids[WPB][CPT + TAIL];   // (char_id, seg_id)
    const int lane = threadIdx.x & 63;
    const int wid  = threadIdx.x >> 6;

    float ht = 0.f, tt = 0.f, hh = 0.f;

    if ((int)blockIdx.x < n_scan_blocks) {
        // ---------------- scan role ----------------
        const int slice = blockIdx.x & 1;      // matches XCD parity (round-robin)
        const int cblk  = blockIdx.x >> 1;
        const int start = (cblk * WPB + wid) * CPT;
        const int nn = min(CPT, total_chars - start);
        const int sl = min(CPT + TAIL, total_chars - start);  // staged length
        const float* __restrict__ cemb = char_emb + slice * HALF + lane;
        const float* __restrict__ eemb = ent + slice * HALF + lane;

        if (nn > 0) {
            for (int i = lane; i < sl; i += 64) {
                s_ids[wid][i] = make_int2(char_ids[start + i], seg_ids[start + i]);
            }
        }
        __syncthreads();

        if (nn > 0) {
            // ---- skip continuation prefix (ballot scan) ----
            int p = 0;
            if (start > 0) {
                const int prev = seg_ids[start - 1];
                p = -1;
                for (int base = 0; base < nn; base += 64) {
                    const int idx = base + lane;
                    const bool differ = (idx < nn) && (s_ids[wid][idx].y != prev);
                    const unsigned long long m = __ballot(differ);
                    if (m) { p = base + (__ffsll((long long)m) - 1); break; }
                }
                if (p < 0) p = nn;   // whole chunk is continuation
            }

            if (p < nn) {
                int cur = s_ids[wid][p].y;
                // prefetch head row for current segment (used at next flush)
                float hv = eemb[(size_t)head_ids[
                    __builtin_amdgcn_readfirstlane(cur)] * DIM];
                float acc = 0.f;
                int c = p;

                float v[BATCH]; int sg[BATCH];
                // prologue: first batch in flight
                if (c + BATCH <= nn) {
#pragma unroll
                    for (int j = 0; j < BATCH; ++j) {
                        const int2 cs = s_ids[wid][c + j];
                        v[j] = cemb[(size_t)cs.x * DIM];
                        sg[j] = cs.y;
                    }
                }
                while (c + BATCH <= nn) {
                    float v2[BATCH]; int sg2[BATCH];
                    const bool have_next = (c + 2 * BATCH <= nn);
                    if (have_next) {
#pragma unroll
                        for (int j = 0; j < BATCH; ++j) {
                            const int2 cs = s_ids[wid][c + BATCH + j];
                            v2[j] = cemb[(size_t)cs.x * DIM]; // next batch in flight
                            sg2[j] = cs.y;
                        }
                    }
#pragma unroll
                    for (int j = 0; j < BATCH; ++j) {
                        if (sg[j] != cur) {               // wave-uniform
                            ht += hv * acc;
                            tt += acc * acc;
                            acc = 0.f;
                            cur = sg[j];
                            hv = eemb[(size_t)head_ids[
                                __builtin_amdgcn_readfirstlane(cur)] * DIM];
                        }
                        acc += v[j];
                    }
                    if (have_next) {
#pragma unroll
                        for (int j = 0; j < BATCH; ++j) { v[j] = v2[j]; sg[j] = sg2[j]; }
                    }
                    c += BATCH;
                }
                // remainder singles (staged, < BATCH)
                for (; c < nn; ++c) {
                    const int2 cs = s_ids[wid][c];
                    if (cs.y != cur) {
                        ht += hv * acc;
                        tt += acc * acc;
                        acc = 0.f;
                        cur = cs.y;
                        hv = eemb[(size_t)head_ids[
                            __builtin_amdgcn_readfirstlane(cur)] * DIM];
                    }
                    acc += cemb[(size_t)cs.x * DIM];
                }

                // ---- tail: last segment may continue past the chunk ----
                int g = nn;
                bool ended = false;
                while (g < sl) {
                    const int idx = g + lane;
                    const bool differ = (idx < sl) && (s_ids[wid][idx].y != cur);
                    const unsigned long long m = __ballot(differ);
                    const int run = m ? (__ffsll((long long)m) - 1)
                                      : min(64, sl - g);
                    int j = 0;
                    while (j < run) {
                        const int mm = min(8, run - j);
                        float vv[8];
#pragma unroll
                        for (int k = 0; k < 8; ++k) {
                            if (k < mm)
                                vv[k] = cemb[(size_t)s_ids[wid][g + j + k].x * DIM];
                        }
                        for (int k = 0; k < mm; ++k) acc += vv[k];
                        j += mm;
                    }
                    g += run;
                    if (m) { ended = true; break; }
                }
                if (!ended && start + sl < total_chars) {
                    // very long run past staged window: rare fallback
                    int gg = start + sl;
                    while (gg < total_chars && seg_ids[gg] == cur) {
                        acc += cemb[(size_t)char_ids[gg] * DIM];
                        ++gg;
                    }
                }
                // final flush
                ht += hv * acc;
                tt += acc * acc;
            }
        }
    } else {
        // ---------------- hh role ----------------
        const int nb = gridDim.x - n_scan_blocks;
        const int stride = nb * WPB;
        const float* __restrict__ e2 = ent + 2 * lane;
        int row = (blockIdx.x - n_scan_blocks) * WPB + wid;
        // 4x unrolled: 4 id loads then 8 row loads in flight
        for (; row + 3 * stride < n_triples; row += 4 * stride) {
            int h0 = head_ids[row];
            int h1 = head_ids[row + stride];
            int h2 = head_ids[row + 2 * stride];
            int h3 = head_ids[row + 3 * stride];
            float a0 = e2[(size_t)h0 * DIM], b0 = e2[(size_t)h0 * DIM + 1];
            float a1 = e2[(size_t)h1 * DIM], b1 = e2[(size_t)h1 * DIM + 1];
            float a2 = e2[(size_t)h2 * DIM], b2 = e2[(size_t)h2 * DIM + 1];
            float a3 = e2[(size_t)h3 * DIM], b3 = e2[(size_t)h3 * DIM + 1];
            hh += a0 * a0 + b0 * b0 + a1 * a1 + b1 * b1 +
                  a2 * a2 + b2 * b2 + a3 * a3 + b3 * b3;
        }
        for (; row < n_triples; row += stride) {
            const int hrow = head_ids[row];
            const float a = e2[(size_t)hrow * DIM];
            const float b = e2[(size_t)hrow * DIM + 1];
            hh += a * a + b * b;
        }
    }

    // ------------- block reduction + atomic -------------
#pragma unroll
    for (int off = 32; off > 0; off >>= 1) {
        ht += __shfl_down(ht, off);
        tt += __shfl_down(tt, off);
        hh += __shfl_down(hh, off);
    }
    __shared__ float r_ht[WPB], r_tt[WPB], r_hh[WPB];
    if (lane == 0) { r_ht[wid] = ht; r_tt[wid] = tt; r_hh[wid] = hh; }
    __syncthreads();
    if (threadIdx.x == 0) {
        float a = 0.f, b = 0.f, c = 0.f;
#pragma unroll
        for (int w = 0; w < WPB; ++w) { a += r_ht[w]; b += r_tt[w]; c += r_hh[w]; }
        if (a != 0.f) atomicAdd(&sums[0], (double)a);
        if (c != 0.f) atomicAdd(&sums[1], (double)c);
        if (b != 0.f) atomicAdd(&sums[2], (double)b);
    }
}

// out = N - ht / (sqrt(hh) * sqrt(tt))
__global__ void finalize_kernel(const double* __restrict__ sums,
                                float* __restrict__ out, int n_triples)
{
    const double ht = sums[0], hh = sums[1], tt = sums[2];
    out[0] = (float)((double)n_triples - ht / sqrt(hh * tt));
}

extern "C" void kernel_launch(void* const* d_in, const int* in_sizes, int n_in,
                              void* d_out, int out_size, void* d_ws, size_t ws_size,
                              hipStream_t stream)
{
    const float* char_emb = (const float*)d_in[0];
    const float* ent_emb  = (const float*)d_in[1];
    const int* head_ids   = (const int*)d_in[2];
    const int* char_ids   = (const int*)d_in[3];
    const int* seg_ids    = (const int*)d_in[4];
    const int n_triples   = in_sizes[2];
    const int total_chars = in_sizes[3];

    double* sums = (double*)d_ws;
    hipMemsetAsync(d_ws, 0, 3 * sizeof(double), stream);

    const int n_streams = (total_chars + CPT - 1) / CPT;
    const int blocks_per_slice = (n_streams + WPB - 1) / WPB;
    const int n_scan_blocks = 2 * blocks_per_slice;
    const int n_hh_blocks = 128;

    fused_kernel<<<n_scan_blocks + n_hh_blocks, 256, 0, stream>>>(
        char_emb, ent_emb, head_ids, char_ids, seg_ids, sums,
        total_chars, n_triples, n_scan_blocks);

    finalize_kernel<<<1, 1, 0, stream>>>(sums, (float*)d_out, n_triples);
}